// Round 12
// baseline (392.169 us; speedup 1.0000x reference)
//
#include <hip/hip_runtime.h>
#include <hip/hip_cooperative_groups.h>
#include <stdint.h>

namespace cg = cooperative_groups;

typedef _Float16 f16;
typedef __attribute__((ext_vector_type(8))) _Float16 f16x8;
typedef __attribute__((ext_vector_type(4))) float    f32x4;

constexpr int NB = 16384;

// packed-weight regions (f16 elem offsets). chunk = 512 f16 = 16 cols x 32 k:
// elem ((nt*KB + kb)*64 + g*16 + rr)*8 + q  <->  W^T[col = nt*16+rr][k = kb*32+g*8+q]
constexpr int OFF_CW1  = 0;        // NT=16, KB=15  (cW1: 464x256)
constexpr int OFF_CW2  = 122880;   // NT=8,  KB=8   (cW2: 256x128)
constexpr int OFF_COW  = 155648;   // NT=32, KB=4   (coW: 128x464, pad 512)
constexpr int OFF_EW1G = 221184;   // NT=72, KB=15  (expW1 4x(464x256) + gateW 12 cols, pad 1152)
constexpr int OFF_EW2  = 774144;   // NT=32, KB=8   (expW2 4x(256x128))
constexpr int PACK_TOTAL = 905216;
constexpr int NCHUNK = PACK_TOTAL / 512;   // 1768

struct KParams {
    const int* disc; const float* cf;
    const float *e0, *e1, *e2, *e3, *e4, *e5, *e6, *e7;
    const float *contW, *contB, *fmW;
    const float *cW1, *cb1, *cW2, *cb2, *coW, *cob;
    const float *expW1, *expb1, *expW2, *expb2;
    const float *gateW, *gateB, *taskW, *taskB, *logv;
    f16 *wp, *xpk, *c1pk, *c2pk, *e1pk;
    float *fm, *gates, *part, *out;
};

__device__ __forceinline__ void g2l16(const void* g, void* l) {
    __builtin_amdgcn_global_load_lds(
        (__attribute__((address_space(1))) void*)(void*)g,
        (__attribute__((address_space(3))) void*)l, 16, 0, 0);
}

// ---------------------------------------------------------------------------
__device__ void pack_chunk(int chunk, int lane, const KParams& p)
{
    const int off = chunk * 512;
    const int rr = lane & 15, gg = lane >> 4;
    float v[8];
    if (off < OFF_CW2) {
        const int cl = off / 512, nt = cl / 15, kb = cl % 15;
        const int n = nt * 16 + rr, k0 = kb * 32 + gg * 8;
#pragma unroll
        for (int q = 0; q < 8; ++q) { const int k = k0 + q; v[q] = (k < 464) ? p.cW1[k * 256 + n] : 0.f; }
    } else if (off < OFF_COW) {
        const int cl = (off - OFF_CW2) / 512, nt = cl / 8, kb = cl % 8;
        const int n = nt * 16 + rr, k0 = kb * 32 + gg * 8;
#pragma unroll
        for (int q = 0; q < 8; ++q) v[q] = p.cW2[(k0 + q) * 128 + n];
    } else if (off < OFF_EW1G) {
        const int cl = (off - OFF_COW) / 512, nt = cl / 4, kb = cl % 4;
        const int n = nt * 16 + rr, k0 = kb * 32 + gg * 8;
#pragma unroll
        for (int q = 0; q < 8; ++q) v[q] = (n < 464) ? p.coW[(k0 + q) * 464 + n] : 0.f;
    } else if (off < OFF_EW2) {
        const int cl = (off - OFF_EW1G) / 512, nt = cl / 15, kb = cl % 15;
        const int n = nt * 16 + rr, k0 = kb * 32 + gg * 8;
        if (n < 1024) {
            const int e = n >> 8, nn = n & 255;
#pragma unroll
            for (int q = 0; q < 8; ++q) { const int k = k0 + q;
                v[q] = (k < 464) ? p.expW1[((size_t)e * 464 + k) * 256 + nn] : 0.f; }
        } else if (n < 1036) {
            const int c = n - 1024;
#pragma unroll
            for (int q = 0; q < 8; ++q) { const int k = k0 + q;
                v[q] = (k < 464) ? p.gateW[((size_t)(c >> 2) * 464 + k) * 4 + (c & 3)] : 0.f; }
        } else {
#pragma unroll
            for (int q = 0; q < 8; ++q) v[q] = 0.f;
        }
    } else {
        const int cl = (off - OFF_EW2) / 512, nt = cl / 8, kb = cl % 8;
        const int n = nt * 16 + rr, k0 = kb * 32 + gg * 8;
        const int e = n >> 7, nn = n & 127;
#pragma unroll
        for (int q = 0; q < 8; ++q) v[q] = p.expW2[((size_t)e * 256 + k0 + q) * 128 + nn];
    }
    f16x8 o;
#pragma unroll
    for (int q = 0; q < 8; ++q) o[q] = (f16)v[q];
    *(f16x8*)(p.wp + (size_t)off + lane * 8) = o;
}

// ---------------------------------------------------------------------------
// counted-vmcnt triple-buffered GEMM pipeline (validated in R10).
// 4 waves (2M x 2N), BM=BN=128. Per slab per wave: 4 g2l16. vmcnt(4) mid-loop.
// ---------------------------------------------------------------------------
template<int KB>
__device__ __forceinline__ void gemm_pipe(
    const f16* __restrict__ Apk, size_t ach0,
    const f16* __restrict__ Bpk, int nt0,
    f16* lA, f16* lB, f32x4 (&acc)[4][4],
    int wave, int lane, int wm, int wn, int g, int rr)
{
    auto issue = [&](int kb) {
        const int buf = kb % 3;
#pragma unroll
        for (int h2 = 0; h2 < 2; ++h2) {
            const int rt = 2 * wave + h2;
            g2l16(Apk + (ach0 + (size_t)rt * KB + kb) * 512 + lane * 8,
                  lA + (size_t)buf * 4096 + rt * 512);
            g2l16(Bpk + ((size_t)(nt0 + rt) * KB + kb) * 512 + lane * 8,
                  lB + (size_t)buf * 4096 + rt * 512);
        }
    };
    issue(0); issue(1);
#pragma unroll
    for (int kb = 0; kb < KB; ++kb) {
        if (kb < KB - 1) asm volatile("s_waitcnt vmcnt(4)" ::: "memory");
        else             asm volatile("s_waitcnt vmcnt(0)" ::: "memory");
        __builtin_amdgcn_s_barrier();
        __builtin_amdgcn_sched_barrier(0);
        if (kb + 2 < KB) issue(kb + 2);
        const f16* A_ = lA + (size_t)(kb % 3) * 4096;
        const f16* B_ = lB + (size_t)(kb % 3) * 4096;
        f16x8 bf[4];
#pragma unroll
        for (int j = 0; j < 4; ++j)
            bf[j] = *(const f16x8*)(B_ + ((wn * 4 + j) * 64 + g * 16 + rr) * 8);
#pragma unroll
        for (int i = 0; i < 4; ++i) {
            const f16x8 af = *(const f16x8*)(A_ + ((wm * 4 + i) * 64 + g * 16 + rr) * 8);
#pragma unroll
            for (int j = 0; j < 4; ++j)
                acc[i][j] = __builtin_amdgcn_mfma_f32_16x16x32_f16(af, bf[j], acc[i][j], 0, 0, 0);
        }
    }
    __syncthreads();
}

// ---------------------------------------------------------------------------
// One kernel, 7 phases. phase=-1: run all with grid.sync (cooperative).
// phase=k>=0: run only phase k (plain launch fallback, stream-ordered).
// ---------------------------------------------------------------------------
__global__ __launch_bounds__(256)
void mmoe_phases(KParams p, int phase)
{
    __shared__ __align__(16) char smem[58368];
    __shared__ const float* stabs[8];
    const bool all = (phase < 0);
    const int t = threadIdx.x, lane = t & 63, wave = t >> 6;
    const int wm = wave >> 1, wn = wave & 1, g = lane >> 4, rr = lane & 15;
    const int bid = blockIdx.x, GD = gridDim.x;

    f16* lA = (f16*)smem;            // 3 slabs x 4096 f16
    f16* lB = (f16*)smem + 12288;

    // ================= phase 0: pack + build =================
    if (all || phase == 0) {
        if (t == 0) {
            stabs[0] = p.e0; stabs[1] = p.e1; stabs[2] = p.e2; stabs[3] = p.e3;
            stabs[4] = p.e4; stabs[5] = p.e5; stabs[6] = p.e6; stabs[7] = p.e7;
        }
        for (int chunk = bid * 4 + wave; chunk < NCHUNK; chunk += GD * 4)
            pack_chunk(chunk, lane, p);

        for (int bb = bid; bb < 512; bb += GD) {   // build: 32 rows per iter
            f16*   xs  = (f16*)smem;               // [32][480]
            float* cfs = (float*)(smem + 30720);   // [32][68]
            float* ctw = (float*)(smem + 39424);   // [64][64]
            float* xes = (float*)(smem + 55808);   // [32][10]
            const long r0 = (long)bb * 32;
            __syncthreads();

            for (int i = t; i < 512; i += 256) xs[(i >> 4) * 480 + 464 + (i & 15)] = (f16)0.f;
            {   // gather: one (row, table) pair per thread
                const int r = t >> 3, tab = t & 7;
                const long fi = p.disc[(r0 + r) * 8 + tab];
                const float* src = stabs[tab] + fi * 50;
                f16* dst = xs + r * 480 + tab * 50;
#pragma unroll
                for (int q = 0; q < 25; ++q) {
                    const float2 v = *(const float2*)(src + q * 2);
                    dst[q * 2] = (f16)v.x; dst[q * 2 + 1] = (f16)v.y;
                }
            }
            for (int i = t; i < 512; i += 256) {
                const int r = i >> 4, q = i & 15;
                const float4 v = *(const float4*)(p.cf + (r0 + r) * 64 + q * 4);
                float* dst = cfs + r * 68 + q * 4;
                dst[0] = v.x; dst[1] = v.y; dst[2] = v.z; dst[3] = v.w;
            }
            for (int i = t; i < 4096; i += 256) ctw[i] = p.contW[i];
            __syncthreads();
            for (int i = t; i < 2048; i += 256) {  // cont -> xs cols 400..463
                const int r = i >> 6, c = i & 63;
                float a = p.contB[c];
#pragma unroll 8
                for (int k = 0; k < 64; ++k) a = fmaf(cfs[r * 68 + k], ctw[k * 64 + c], a);
                xs[r * 480 + 400 + c] = (f16)fmaxf(a, 0.f);
            }
            __syncthreads();
            for (int i = t; i < 320; i += 256) {   // xe = x @ fmW
                const int r = i / 10, jj = i - (i / 10) * 10;
                float a = 0.f;
                for (int d = 0; d < 464; ++d)
                    a = fmaf((float)xs[r * 480 + d], p.fmW[d * 10 + jj], a);
                xes[r * 10 + jj] = a;
            }
            for (int si = t; si < 1920; si += 256) {  // packed x write
                const int rt = si / 960, rem = si - rt * 960;
                const int kb = rem >> 6, slot = rem & 63;
                *(f16x8*)(p.xpk + ((size_t)(bb * 2 + rt) * 15 + kb) * 512 + slot * 8)
                    = *(const f16x8*)(xs + (rt * 16 + (slot & 15)) * 480 + kb * 32 + (slot >> 4) * 8);
            }
            __syncthreads();
            if (t < 32) {
                float s = 0.f, ss = 0.f;
#pragma unroll
                for (int j = 0; j < 10; ++j) { const float v = xes[t * 10 + j]; s += v; ss += v * v; }
                p.fm[r0 + t] = 0.5f * (s * s - ss);
            }
        }
    }
    if (all) cg::this_grid().sync();

    // ================= phase 1: c1 (256 tiles) =================
    if (all || phase == 1)
    for (int tile = bid; tile < 256; tile += GD) {
        const int ct = tile >> 7, by = tile & 127;
        f32x4 acc[4][4] = {};
        gemm_pipe<15>(p.xpk, (size_t)by * 120, p.wp + OFF_CW1, ct * 8,
                      lA, lB, acc, wave, lane, wm, wn, g, rr);
        const int rowb = by * 128 + wm * 64;
#pragma unroll
        for (int j = 0; j < 4; ++j) {
            const int col = ct * 128 + wn * 64 + j * 16 + rr;
            const float bv = p.cb1[col];
            const int kbo = col >> 5, go = (col >> 3) & 3, qo = col & 7;
#pragma unroll
            for (int i = 0; i < 4; ++i)
#pragma unroll
                for (int rg = 0; rg < 4; ++rg) {
                    const int row = rowb + i * 16 + g * 4 + rg;
                    p.c1pk[(((size_t)(row >> 4) * 8 + kbo) * 64 + go * 16 + (row & 15)) * 8 + qo]
                        = (f16)fmaxf(acc[i][j][rg] + bv, 0.f);
                }
        }
    }
    if (all) cg::this_grid().sync();

    // ================= phase 2: c2 (128 tiles) =================
    if (all || phase == 2)
    for (int tile = bid; tile < 128; tile += GD) {
        const int by = tile;
        f32x4 acc[4][4] = {};
        gemm_pipe<8>(p.c1pk, (size_t)by * 64, p.wp + OFF_CW2, 0,
                     lA, lB, acc, wave, lane, wm, wn, g, rr);
        const int rowb = by * 128 + wm * 64;
#pragma unroll
        for (int j = 0; j < 4; ++j) {
            const int col = wn * 64 + j * 16 + rr;
            const float bv = p.cb2[col];
            const int kbo = col >> 5, go = (col >> 3) & 3, qo = col & 7;
#pragma unroll
            for (int i = 0; i < 4; ++i)
#pragma unroll
                for (int rg = 0; rg < 4; ++rg) {
                    const int row = rowb + i * 16 + g * 4 + rg;
                    p.c2pk[(((size_t)(row >> 4) * 4 + kbo) * 64 + go * 16 + (row & 15)) * 8 + qo]
                        = (f16)fmaxf(acc[i][j][rg] + bv, 0.f);
                }
        }
    }
    if (all) cg::this_grid().sync();

    // ================= phase 3: h (512 tiles) =================
    if (all || phase == 3)
    for (int tile = bid; tile < 512; tile += GD) {
        const int ct = tile >> 7, by = tile & 127;
        f32x4 acc[4][4] = {};
        gemm_pipe<4>(p.c2pk, (size_t)by * 32, p.wp + OFF_COW, ct * 8,
                     lA, lB, acc, wave, lane, wm, wn, g, rr);
        const int ct4 = ct * 4;
        for (int c = wave; c < 32; c += 4) {     // stage x tile into smem
            const int rt_l = c >> 2, kbl = c & 3;
            if (ct4 + kbl < 15)
                g2l16(p.xpk + ((size_t)(by * 8 + rt_l) * 15 + ct4 + kbl) * 512 + lane * 8,
                      (f16*)smem + (size_t)c * 512);
        }
        asm volatile("s_waitcnt vmcnt(0)" ::: "memory");
        __syncthreads();
        const int rowb = by * 128 + wm * 64;
#pragma unroll
        for (int j = 0; j < 4; ++j) {
            const int col = ct * 128 + wn * 64 + j * 16 + rr;
            if (col < 464) {
                const float bv = p.cob[col];
                const int kbl = (col >> 5) & 3, go = (col >> 3) & 3, qo = col & 7;
#pragma unroll
                for (int i = 0; i < 4; ++i)
#pragma unroll
                    for (int rg = 0; rg < 4; ++rg) {
                        const int row = rowb + i * 16 + g * 4 + rg;
                        const int cc = (wm * 4 + i) * 4 + kbl;
                        const float xv = (float)((f16*)smem)[((size_t)cc * 64 + go * 16 + (g * 4 + rg)) * 8 + qo];
                        const float hv = acc[i][j][rg] + bv + xv + p.fm[row];
                        p.xpk[(((size_t)(row >> 4) * 15 + (col >> 5)) * 64 + go * 16 + (row & 15)) * 8 + qo]
                            = (f16)hv;
                    }
            }
        }
        __syncthreads();
    }
    if (all) cg::this_grid().sync();

    // ================= phase 4: e1 + gates (1152 tiles) =================
    if (all || phase == 4)
    for (int tile = bid; tile < 1152; tile += GD) {
        const int ct = tile / 128, by = tile - ct * 128;
        f32x4 acc[4][4] = {};
        gemm_pipe<15>(p.xpk, (size_t)by * 120, p.wp + OFF_EW1G, ct * 8,
                      lA, lB, acc, wave, lane, wm, wn, g, rr);
        const int rowb = by * 128 + wm * 64;
        if (ct < 8) {
#pragma unroll
            for (int j = 0; j < 4; ++j) {
                const int col = ct * 128 + wn * 64 + j * 16 + rr;
                const int e = col >> 8, cl = col & 255;
                const float bv = p.expb1[col];
                const int kbo = cl >> 5, go = (cl >> 3) & 3, qo = cl & 7;
                f16* dst = p.e1pk + (size_t)e * NB * 256;
#pragma unroll
                for (int i = 0; i < 4; ++i)
#pragma unroll
                    for (int rg = 0; rg < 4; ++rg) {
                        const int row = rowb + i * 16 + g * 4 + rg;
                        dst[(((size_t)(row >> 4) * 8 + kbo) * 64 + go * 16 + (row & 15)) * 8 + qo]
                            = (f16)fmaxf(acc[i][j][rg] + bv, 0.f);
                    }
            }
        } else if (wn == 0) {
            const float gb = (rr < 12) ? p.gateB[rr] : 0.f;
#pragma unroll
            for (int i = 0; i < 4; ++i)
#pragma unroll
                for (int rg = 0; rg < 4; ++rg) {
                    const float v = acc[i][0][rg] + gb;
                    float m = fmaxf(v, __shfl_xor(v, 1, 64));
                    m = fmaxf(m, __shfl_xor(m, 2, 64));
                    const float pr = __expf(v - m);
                    float s = pr + __shfl_xor(pr, 1, 64);
                    s += __shfl_xor(s, 2, 64);
                    if (rr < 12) {
                        const long row = rowb + i * 16 + g * 4 + rg;
                        p.gates[row * 12 + rr] = pr / s;
                    }
                }
        }
    }
    if (all) cg::this_grid().sync();

    // ================= phase 5: e2 + task-dot (512 tiles) =================
    if (all || phase == 5)
    for (int tile = bid; tile < 512; tile += GD) {
        const int z = tile >> 7, by = tile & 127;
        float* sh_s = (float*)(smem + 49152);    // [2][2][64][3]
        f32x4 acc[4][4] = {};
        gemm_pipe<8>(p.e1pk + (size_t)z * NB * 256, (size_t)by * 64, p.wp + OFF_EW2, z * 8,
                     lA, lB, acc, wave, lane, wm, wn, g, rr);
        float tws[3][4], bj[4];
#pragma unroll
        for (int j = 0; j < 4; ++j) {
            const int col = wn * 64 + j * 16 + rr;
            bj[j] = p.expb2[z * 128 + col];
#pragma unroll
            for (int tt = 0; tt < 3; ++tt) tws[tt][j] = p.taskW[tt * 128 + col];
        }
#pragma unroll
        for (int i = 0; i < 4; ++i)
#pragma unroll
            for (int rg = 0; rg < 4; ++rg) {
                float p0 = 0.f, p1 = 0.f, p2 = 0.f;
#pragma unroll
                for (int j = 0; j < 4; ++j) {
                    const float v = acc[i][j][rg] + bj[j];
                    p0 = fmaf(v, tws[0][j], p0);
                    p1 = fmaf(v, tws[1][j], p1);
                    p2 = fmaf(v, tws[2][j], p2);
                }
#pragma unroll
                for (int off = 1; off < 16; off <<= 1) {
                    p0 += __shfl_xor(p0, off, 64);
                    p1 += __shfl_xor(p1, off, 64);
                    p2 += __shfl_xor(p2, off, 64);
                }
                if (rr == 0) {
                    const int rl = i * 16 + g * 4 + rg;
                    sh_s[((wm * 2 + wn) * 64 + rl) * 3 + 0] = p0;
                    sh_s[((wm * 2 + wn) * 64 + rl) * 3 + 1] = p1;
                    sh_s[((wm * 2 + wn) * 64 + rl) * 3 + 2] = p2;
                }
            }
        __syncthreads();
        for (int idx = t; idx < 128 * 3; idx += 256) {
            const int rl = idx / 3, tt = idx - rl * 3;
            const int wmm = rl >> 6, r2 = rl & 63;
            const float s = sh_s[((wmm * 2 + 0) * 64 + r2) * 3 + tt] +
                            sh_s[((wmm * 2 + 1) * 64 + r2) * 3 + tt];
            const long row = (long)by * 128 + rl;
            p.part[((size_t)z * NB + row) * 3 + tt] = p.gates[row * 12 + tt * 4 + z] * s;
        }
        __syncthreads();
    }
    if (all) cg::this_grid().sync();

    // ================= phase 6: finalize =================
    if (all || phase == 6)
    for (int idx = bid * 256 + t; idx < NB * 3; idx += GD * 256) {
        const int row = idx / 3, tt = idx - row * 3;
        p.out[idx] = p.part[(size_t)row * 3 + tt] +
                     p.part[(size_t)NB * 3 + row * 3 + tt] +
                     p.part[(size_t)NB * 6 + row * 3 + tt] +
                     p.part[(size_t)NB * 9 + row * 3 + tt] + p.taskB[tt];
        if (idx < 3) p.out[(size_t)NB * 3 + idx] = p.logv[idx];
    }
}

// ---------------------------------------------------------------------------
extern "C" void kernel_launch(void* const* d_in, const int* in_sizes, int n_in,
                              void* d_out, int out_size, void* d_ws, size_t ws_size,
                              hipStream_t stream)
{
    (void)in_sizes; (void)n_in; (void)out_size; (void)ws_size;

    char* w = (char*)d_ws;
    f16* wp      = (f16*)w;   w += (size_t)PACK_TOTAL * 2;
    f16* xpk     = (f16*)w;   w += (size_t)NB * 480 * 2;
    f16* c1pk    = (f16*)w;   w += (size_t)NB * 256 * 2;
    f16* c2pk    = (f16*)w;   w += (size_t)NB * 128 * 2;
    f16* e1pk    = (f16*)w;   w += (size_t)4 * NB * 256 * 2;
    float* fm    = (float*)w; w += (size_t)NB * 4;
    float* gates = (float*)w; w += (size_t)NB * 12 * 4;
    float* part  = (float*)w; w += (size_t)4 * NB * 3 * 4;

    KParams p;
    p.disc  = (const int*)  d_in[0];
    p.cf    = (const float*)d_in[1];
    p.e0 = (const float*)d_in[2]; p.e1 = (const float*)d_in[3];
    p.e2 = (const float*)d_in[4]; p.e3 = (const float*)d_in[5];
    p.e4 = (const float*)d_in[6]; p.e5 = (const float*)d_in[7];
    p.e6 = (const float*)d_in[8]; p.e7 = (const float*)d_in[9];
    p.contW = (const float*)d_in[10]; p.contB = (const float*)d_in[11];
    p.fmW   = (const float*)d_in[12];
    p.cW1 = (const float*)d_in[13]; p.cb1 = (const float*)d_in[14];
    p.cW2 = (const float*)d_in[15]; p.cb2 = (const float*)d_in[16];
    p.coW = (const float*)d_in[17]; p.cob = (const float*)d_in[18];
    p.expW1 = (const float*)d_in[19]; p.expb1 = (const float*)d_in[20];
    p.expW2 = (const float*)d_in[21]; p.expb2 = (const float*)d_in[22];
    p.gateW = (const float*)d_in[23]; p.gateB = (const float*)d_in[24];
    p.taskW = (const float*)d_in[25]; p.taskB = (const float*)d_in[26];
    p.logv  = (const float*)d_in[27];
    p.wp = wp; p.xpk = xpk; p.c1pk = c1pk; p.c2pk = c2pk; p.e1pk = e1pk;
    p.fm = fm; p.gates = gates; p.part = part; p.out = (float*)d_out;

    // Compute a co-residency-safe grid; fall back to plain phase launches
    // if the cooperative launch is rejected.
    int occ = 0;
    if (hipOccupancyMaxActiveBlocksPerMultiprocessor(
            &occ, (const void*)mmoe_phases, 256, 0) != hipSuccess || occ < 1)
        occ = 1;
    int ncu = 0;
    if (hipDeviceGetAttribute(&ncu, hipDeviceAttributeMultiprocessorCount, 0)
            != hipSuccess || ncu < 1)
        ncu = 256;
    int grid = occ * ncu;
    if (grid > 512) grid = 512;

    int ph = -1;
    void* args[] = { &p, &ph };
    hipError_t le = hipLaunchCooperativeKernel((const void*)mmoe_phases,
                                               dim3(grid), dim3(256),
                                               args, 0, stream);
    if (le != hipSuccess) {
        for (int k = 0; k < 7; ++k)
            mmoe_phases<<<512, 256, 0, stream>>>(p, k);
    }
}